// Round 16
// baseline (111.793 us; speedup 1.0000x reference)
//
#include <hip/hip_runtime.h>
#include <hip/hip_bf16.h>
#include <stdint.h>

#define S_ATOMS 25
#define DIM 64
#define AP 40      // hT row stride (shorts): 80B rows (16B-aligned for b128)
#define VP 72      // v' row stride (shorts): 144B rows
#define WAVES 4    // waves per block (256 threads)
#define PM 5       // molecules per wave (sequential, 1 live at a time)
#define BMOLS 20   // molecules per gnn block = WAVES*PM = bucket size
#define XB2 2560   // shorts per wave buffer: max(64*AP, 32*VP) = 2560 (5120B)
#define EPB 16384  // edges per scatter block
#define CAP 2560   // sorted capacity per bucket (E[edges]=2000, +12 sigma)

typedef __attribute__((ext_vector_type(8))) short short8;   // 8 bf16
typedef __attribute__((ext_vector_type(4))) short short4s;  // 4 bf16 (b64)
typedef __attribute__((ext_vector_type(4))) float f32x4;
typedef __attribute__((ext_vector_type(4))) unsigned uint4v;

static __device__ __forceinline__ short bf(float x) {
    return (short)__builtin_bit_cast(unsigned short, __float2bfloat16(x));
}
// v_cvt_pk_bf16_f32: dst.lo = bf16(lo), dst.hi = bf16(hi) — 1 instr, RNE
static __device__ __forceinline__ unsigned cvtpk(float lo, float hi) {
    unsigned r;
    asm("v_cvt_pk_bf16_f32 %0, %1, %2" : "=v"(r) : "v"(lo), "v"(hi));
    return r;
}

// ---------------- prep_k: zero cursor/hist (+ optional W-pack/embT) ---------
__global__ __launch_bounds__(256) void prep_k(
    const float* __restrict__ W_fp, const float* __restrict__ emb,
    unsigned* __restrict__ zbuf, short* __restrict__ wpk, short* __restrict__ embT,
    int LH, int NF, int nzero, int doEmb)
{
    int gid = blockIdx.x * 256 + threadIdx.x;
    if (gid < nzero) {                // zero bucket cursors (or fallback hist)
        uint4v z; z[0]=0; z[1]=0; z[2]=0; z[3]=0;
        ((uint4v*)zbuf)[gid] = z;
    }
    if (gid < LH * 512) {             // prepack W_fp MFMA B-fragments (fallback)
        int t = gid;
        int layer = t >> 9, q = t & 511;
        int nt = q >> 7, ks = (q >> 6) & 1, lane = q & 63;
        int cc = lane & 15, gg = lane >> 4;
        const float* p = W_fp + (size_t)layer * 4096 + (nt * 16 + cc) * 64 + ks * 32 + 8 * gg;
        short8 s;
        #pragma unroll
        for (int j = 0; j < 8; ++j) s[j] = bf(p[j]);
        *(short8*)(wpk + (size_t)t * 8) = s;
    }
    if (doEmb && gid < NF * 8) {      // emb f32 -> bf16 row-major (fallback)
        int row = gid >> 3, seg = gid & 7;
        const float* p = emb + (size_t)row * DIM + seg * 8;
        short8 s;
        #pragma unroll
        for (int j = 0; j < 8; ++j) s[j] = bf(p[j]);
        *(short8*)(embT + (size_t)row * DIM + seg * 8) = s;
    }
}

// ---------------- scatter_k: self-ticketing counting sort + fused prep ------
// bucket b = mol / 20 (= src/500). key16 = (mol%20)*640 + dl*25 + sl (<12800)
// Bucket fill ORDER is nondeterministic; gnn's histogram SUM is not.
__global__ __launch_bounds__(256) void scatter_k(
    const int* __restrict__ esrc, const int* __restrict__ edst,
    unsigned* __restrict__ gcur, unsigned short* __restrict__ sorted,
    const float* __restrict__ W_fp, const float* __restrict__ emb,
    short* __restrict__ wpk, short* __restrict__ embT,
    int E, int NBUK, int LH, int NF)
{
    extern __shared__ unsigned cnt[];               // NBUK words
    // ---- fused prep: W-pack + emb->bf16 (grid-stride, overlaps counting) ----
    int gid = blockIdx.x * 256 + threadIdx.x;
    int gs  = gridDim.x * 256;
    for (int t = gid; t < LH * 512; t += gs) {
        int layer = t >> 9, q = t & 511;
        int nt = q >> 7, ks = (q >> 6) & 1, lane = q & 63;
        int cc = lane & 15, gg = lane >> 4;
        const float* p = W_fp + (size_t)layer * 4096 + (nt * 16 + cc) * 64 + ks * 32 + 8 * gg;
        short8 s;
        #pragma unroll
        for (int j = 0; j < 8; ++j) s[j] = bf(p[j]);
        *(short8*)(wpk + (size_t)t * 8) = s;
    }
    for (int t = gid; t < NF * 8; t += gs) {
        int row = t >> 3, seg = t & 7;
        const float* p = emb + (size_t)row * DIM + seg * 8;
        short8 s;
        #pragma unroll
        for (int j = 0; j < 8; ++j) s[j] = bf(p[j]);
        *(short8*)(embT + (size_t)row * DIM + seg * 8) = s;
    }

    // ---- pass1: count this block's edges per bucket ----
    for (int j = threadIdx.x; j < NBUK; j += 256) cnt[j] = 0;
    __syncthreads();
    int base = blockIdx.x * EPB;
    int end = base + EPB; if (end > E) end = E;
    int e = base + threadIdx.x * 4;
    for (; e + 4 <= end; e += 1024) {               // int4 reads, 4 edges/thread
        int4 s4 = *(const int4*)(esrc + e);
        atomicAdd(&cnt[s4.x / (S_ATOMS * BMOLS)], 1u);
        atomicAdd(&cnt[s4.y / (S_ATOMS * BMOLS)], 1u);
        atomicAdd(&cnt[s4.z / (S_ATOMS * BMOLS)], 1u);
        atomicAdd(&cnt[s4.w / (S_ATOMS * BMOLS)], 1u);
    }
    for (; e < end; ++e)
        atomicAdd(&cnt[esrc[e] / (S_ATOMS * BMOLS)], 1u);
    __syncthreads();
    // ---- ticket: claim [base, base+cnt) per bucket; LDS holds write cursor --
    for (int j = threadIdx.x; j < NBUK; j += 256) {
        unsigned cj = cnt[j];
        unsigned b0 = cj ? atomicAdd(&gcur[j], cj) : 0u;
        if (b0 > CAP) b0 = CAP;
        cnt[j] = (unsigned)j * CAP + b0;
    }
    __syncthreads();
    // ---- pass2: scatter compact u16 keys ----
    for (int e2 = base + threadIdx.x; e2 < end; e2 += 256) {
        int s = esrc[e2], d = edst[e2];
        int m  = s / S_ATOMS;
        int sl = s - m * S_ATOMS;
        int dl = d - m * S_ATOMS;
        int b  = s / (S_ATOMS * BMOLS);
        int ml = m - b * BMOLS;
        unsigned pos = atomicAdd(&cnt[b], 1u);
        if (pos < (unsigned)(b + 1) * CAP)
            sorted[pos] = (unsigned short)(ml * 640 + dl * 25 + sl);
    }
}

// ---------------- fused per-molecule GNN ------------------------------------
// SORTED: block=bucket(20 mols), B-hists built in LDS from sorted keys
// GEMM1: h[atom][dout] = v*W^T (A=v, B=Wpack)       -> 16 MFMA
// GEMM2: u^T[dim][atom] = h^T * B^T = mfma(b2,amat) -> 8 MFMA,  B = I + A
template<bool SORTED, bool FAST>
__global__ __launch_bounds__(256, 4) void gnn_k(
    const float* __restrict__ emb,     // [NF,64] f32 (FAST=false)
    const short* __restrict__ embT,    // [NF,64] bf16 (FAST=true)
    const float* __restrict__ b_fp, const float* __restrict__ W_out,
    const float* __restrict__ b_out, const float* __restrict__ W_prop,
    const float* __restrict__ b_prop, const int* __restrict__ fps,
    const unsigned* __restrict__ Bg,   // global nibble hist (SORTED=false)
    const unsigned short* __restrict__ sorted,  // [NBUK*CAP] (SORTED=true)
    const unsigned* __restrict__ gcur, // [NBUK] final counts (SORTED=true)
    const short* __restrict__ wpk, float* __restrict__ out,
    int LH, int LO, int M)
{
    __shared__ __align__(16) short xb_all[WAVES][XB2];
    __shared__ __align__(16) float mv_all[WAVES][PM][DIM];
    __shared__ unsigned bh[BMOLS * 80];   // 20 mols x 640 nibbles (80 words)
    const int w = threadIdx.x >> 6, l = threadIdx.x & 63;
    const int c = l & 15, g = l >> 4;
    short* xb = xb_all[w];
    const short8* wp8 = (const short8*)wpk;
    const int wave_id = blockIdx.x * WAVES + w;

    if (SORTED) {
        for (int j = threadIdx.x; j < BMOLS * 80; j += 256) bh[j] = 0;
        __syncthreads();
        unsigned cb = gcur[blockIdx.x]; if (cb > CAP) cb = CAP;
        const unsigned short* sp = sorted + (size_t)blockIdx.x * CAP;
        for (int i = threadIdx.x; i < (int)cb; i += 256) {
            unsigned k = sp[i];
            atomicAdd(&bh[k >> 3], 1u << ((k & 7) * 4));
        }
        __syncthreads();
    }

    for (int mi = 0; mi < PM; ++mi) {
        const int mol = wave_id * PM + mi;
        if (mol >= M) break;           // wave-uniform

        // ---- amat: B^T-operand frags, B = I + A ----
        const int ml = w * PM + mi;    // mol within block (SORTED)
        short8 amat[2];
        #pragma unroll
        for (int at = 0; at < 2; ++at) {
            int row = at * 16 + c;
            float f[8];
            if (row < S_ATOMS) {
                unsigned lo, hi; int sh;
                if (SORTED) {
                    int n0 = ml * 640 + row * 25 + 8 * g;
                    lo = bh[n0 >> 3]; hi = bh[(n0 >> 3) + 1];
                    sh = (n0 & 7) * 4;
                } else {
                    int n0 = mol * 625 + row * 25 + 8 * g;
                    lo = Bg[n0 >> 3]; hi = Bg[(n0 >> 3) + 1];
                    sh = (n0 & 7) * 4;
                }
                unsigned long long v64 = ((unsigned long long)hi << 32) | lo;
                v64 >>= sh;
                #pragma unroll
                for (int j = 0; j < 8; ++j) {
                    unsigned n = (unsigned)(v64 >> (4 * j)) & 0xFu;
                    f[j] = (8 * g + j) < S_ATOMS ? (float)n : 0.f;
                    if (8 * g + j == row) f[j] += 1.0f;   // +I
                }
            } else {
                #pragma unroll
                for (int j = 0; j < 8; ++j) f[j] = 0.f;
            }
            short8 s;
            #pragma unroll
            for (int j = 0; j < 8; ++j) s[j] = bf(f[j]);
            amat[at] = s;
        }

        // ---- layer-0 A-frags from the embedding table ----
        short8 a1[2][2];
        #pragma unroll
        for (int mt = 0; mt < 2; ++mt) {
            int atom = mt * 16 + c;
            int aa = atom < S_ATOMS ? atom : S_ATOMS - 1;  // pads killed by B cols=0
            int fi = fps[mol * S_ATOMS + aa];
            #pragma unroll
            for (int ks = 0; ks < 2; ++ks) {
                if (FAST) {
                    a1[mt][ks] = *(const short8*)(embT + (size_t)fi * DIM + ks * 32 + 8 * g);
                } else {
                    const float4* qp = (const float4*)(emb + (size_t)fi * DIM + ks * 32 + 8 * g);
                    float4 f0 = qp[0], f1 = qp[1];
                    short8 s;
                    s[0]=bf(f0.x); s[1]=bf(f0.y); s[2]=bf(f0.z); s[3]=bf(f0.w);
                    s[4]=bf(f1.x); s[5]=bf(f1.y); s[6]=bf(f1.z); s[7]=bf(f1.w);
                    a1[mt][ks] = s;
                }
            }
        }

        for (int layer = 0; layer < LH; ++layer) {
            // ---- GEMM1: acc = v*W^T + b ----
            float bv[4];
            #pragma unroll
            for (int nt = 0; nt < 4; ++nt) bv[nt] = b_fp[layer * DIM + nt * 16 + c];
            f32x4 acc[2][4];
            #pragma unroll
            for (int mt = 0; mt < 2; ++mt)
                #pragma unroll
                for (int nt = 0; nt < 4; ++nt) {
                    f32x4 a; a[0]=bv[nt]; a[1]=bv[nt]; a[2]=bv[nt]; a[3]=bv[nt];
                    acc[mt][nt] = a;
                }
            #pragma unroll
            for (int ks = 0; ks < 2; ++ks) {
                short8 bwk[4];
                #pragma unroll
                for (int nt = 0; nt < 4; ++nt)
                    bwk[nt] = wp8[layer * 512 + nt * 128 + ks * 64 + l];
                #pragma unroll
                for (int mt = 0; mt < 2; ++mt)
                    #pragma unroll
                    for (int nt = 0; nt < 4; ++nt)
                        acc[mt][nt] = __builtin_amdgcn_mfma_f32_16x16x32_bf16(
                            a1[mt][ks], bwk[nt], acc[mt][nt], 0, 0, 0);
            }

            // ---- epilogue1: relu, cvt_pk pack, write hT[dout][atom] ----
            #pragma unroll
            for (int mt = 0; mt < 2; ++mt)
                #pragma unroll
                for (int nt = 0; nt < 4; ++nt) {
                    unsigned w0 = cvtpk(fmaxf(acc[mt][nt][0], 0.f),
                                        fmaxf(acc[mt][nt][1], 0.f));
                    unsigned w1 = cvtpk(fmaxf(acc[mt][nt][2], 0.f),
                                        fmaxf(acc[mt][nt][3], 0.f));
                    *(uint2*)&xb[(nt * 16 + c) * AP + mt * 16 + 4 * g] = make_uint2(w0, w1);
                }
            __builtin_amdgcn_wave_barrier();

            // ---- GEMM2: u^T = h^T * B^T ----
            short8 b2[4];
            #pragma unroll
            for (int dt = 0; dt < 4; ++dt)
                b2[dt] = *(const short8*)&xb[(dt * 16 + c) * AP + 8 * g];
            f32x4 ua[4][2];
            #pragma unroll
            for (int dt = 0; dt < 4; ++dt)
                #pragma unroll
                for (int at = 0; at < 2; ++at) {
                    f32x4 z; z[0]=0.f; z[1]=0.f; z[2]=0.f; z[3]=0.f;
                    ua[dt][at] = __builtin_amdgcn_mfma_f32_16x16x32_bf16(
                        b2[dt], amat[at], z, 0, 0, 0);
                }

            // ---- per-atom norms (atom = at*16+c; reduce over g-groups) ----
            float ss0 = 0.f, ss1 = 0.f;
            #pragma unroll
            for (int dt = 0; dt < 4; ++dt)
                #pragma unroll
                for (int r = 0; r < 4; ++r) {
                    ss0 += ua[dt][0][r] * ua[dt][0][r];
                    ss1 += ua[dt][1][r] * ua[dt][1][r];
                }
            ss0 += __shfl_xor(ss0, 16); ss0 += __shfl_xor(ss0, 32);
            ss1 += __shfl_xor(ss1, 16); ss1 += __shfl_xor(ss1, 32);
            float rn0 = __builtin_amdgcn_rsqf(fmaxf(ss0, 1e-24f));
            float rn1 = __builtin_amdgcn_rsqf(fmaxf(ss1, 1e-24f));

            bool lastl = (layer == LH - 1);
            __builtin_amdgcn_wave_barrier();
            if (!lastl) {
                // ---- v' -> xb[atom][dim] via cvt_pk (b2 already in regs) ----
                #pragma unroll
                for (int at = 0; at < 2; ++at) {
                    float r0 = at ? rn1 : rn0;
                    #pragma unroll
                    for (int dt = 0; dt < 4; ++dt) {
                        unsigned w0 = cvtpk(ua[dt][at][0] * r0, ua[dt][at][1] * r0);
                        unsigned w1 = cvtpk(ua[dt][at][2] * r0, ua[dt][at][3] * r0);
                        *(uint2*)&xb[(at * 16 + c) * VP + dt * 16 + 4 * g] = make_uint2(w0, w1);
                    }
                }
                __builtin_amdgcn_wave_barrier();
                #pragma unroll
                for (int mt = 0; mt < 2; ++mt)
                    #pragma unroll
                    for (int ks = 0; ks < 2; ++ks)
                        a1[mt][ks] = *(const short8*)&xb[(mt * 16 + c) * VP + ks * 32 + 8 * g];
            } else {
                // ---- molecule sum via 15-shfl split-butterfly over c-lanes ----
                float mx[16];
                #pragma unroll
                for (int dt = 0; dt < 4; ++dt)
                    #pragma unroll
                    for (int r = 0; r < 4; ++r)
                        mx[dt * 4 + r] = ua[dt][0][r] * rn0 + ua[dt][1][r] * rn1;
                #pragma unroll
                for (int k = 0; k < 8; ++k) {
                    float send = (c & 8) ? mx[k] : mx[k + 8];
                    float keep = (c & 8) ? mx[k + 8] : mx[k];
                    mx[k] = keep + __shfl_xor(send, 8);
                }
                #pragma unroll
                for (int k = 0; k < 4; ++k) {
                    float send = (c & 4) ? mx[k] : mx[k + 4];
                    float keep = (c & 4) ? mx[k + 4] : mx[k];
                    mx[k] = keep + __shfl_xor(send, 4);
                }
                #pragma unroll
                for (int k = 0; k < 2; ++k) {
                    float send = (c & 2) ? mx[k] : mx[k + 2];
                    float keep = (c & 2) ? mx[k + 2] : mx[k];
                    mx[k] = keep + __shfl_xor(send, 2);
                }
                {
                    float send = (c & 1) ? mx[0] : mx[1];
                    float keep = (c & 1) ? mx[1] : mx[0];
                    mx[0] = keep + __shfl_xor(send, 1);
                }
                int dim = (c >> 2) * 16 + 4 * g + (c & 3);
                mv_all[w][mi][dim] = mx[0];
                __builtin_amdgcn_wave_barrier();
            }
        }
    }

    // ---- output MLP, batched over the wave's PM molecules (lane = dout) ----
    float cur[PM];
    for (int layer = 0; layer < LO; ++layer) {
        const float4* wr = (const float4*)(W_out + ((size_t)layer * DIM + l) * DIM);
        float bb = b_out[layer * DIM + l];
        float av[PM];
        #pragma unroll
        for (int q = 0; q < PM; ++q) av[q] = bb;
        #pragma unroll
        for (int k = 0; k < 16; ++k) {
            float4 ww = wr[k];
            #pragma unroll
            for (int q = 0; q < PM; ++q) {
                float4 vv = ((const float4*)mv_all[w][q])[k];
                av[q] += vv.x * ww.x + vv.y * ww.y + vv.z * ww.z + vv.w * ww.w;
            }
        }
        __builtin_amdgcn_wave_barrier();
        #pragma unroll
        for (int q = 0; q < PM; ++q) { cur[q] = fmaxf(av[q], 0.f); mv_all[w][q][l] = cur[q]; }
        __builtin_amdgcn_wave_barrier();
    }
    float wpv = W_prop[l], bp = b_prop[0];
    #pragma unroll
    for (int q = 0; q < PM; ++q) {
        float p = cur[q] * wpv;
        p += __shfl_xor(p, 1);  p += __shfl_xor(p, 2);
        p += __shfl_xor(p, 4);  p += __shfl_xor(p, 8);
        p += __shfl_xor(p, 16); p += __shfl_xor(p, 32);
        int mol = wave_id * PM + q;
        if (l == 0 && mol < M) out[mol] = p + bp;
    }
}

// ---------------- fallback ehist (global memory-side atomics) ---------------
__global__ __launch_bounds__(256) void ehist_k(
    const int* __restrict__ esrc, const int* __restrict__ edst,
    unsigned* __restrict__ Bg, int E)
{
    int e = blockIdx.x * 256 + threadIdx.x;
    if (e >= E) return;
    int s = esrc[e], d = edst[e];
    int m  = s / S_ATOMS;
    int sl = s - m * S_ATOMS;
    int dl = d - m * S_ATOMS;
    int n = m * 625 + dl * 25 + sl;
    atomicAdd(&Bg[n >> 3], 1u << ((n & 7) * 4));
}

// ---------------- launch ----------------------------------------------------
extern "C" void kernel_launch(void* const* d_in, const int* in_sizes, int n_in,
                              void* d_out, int out_size, void* d_ws, size_t ws_size,
                              hipStream_t stream)
{
    const float* emb    = (const float*)d_in[0];
    const float* W_fp   = (const float*)d_in[1];
    const float* b_fp   = (const float*)d_in[2];
    const float* W_out  = (const float*)d_in[3];
    const float* b_out  = (const float*)d_in[4];
    const float* W_prop = (const float*)d_in[5];
    const float* b_prop = (const float*)d_in[6];
    const int*   fps    = (const int*)d_in[7];
    const int*   esrc   = (const int*)d_in[8];
    const int*   edst   = (const int*)d_in[9];

    const int T  = in_sizes[7];
    const int E  = in_sizes[8];
    const int NF = in_sizes[0] / DIM;
    const int LH = in_sizes[1] / (DIM * DIM);
    const int LO = in_sizes[3] / (DIM * DIM);
    const int M  = T / S_ATOMS;

    const int NBUK = (M + BMOLS - 1) / BMOLS;
    const int NBLK = (E + EPB - 1) / EPB;
    const int grid = (M + WAVES * PM - 1) / (WAVES * PM);  // == NBUK

    auto al = [](size_t x) { return (x + 255) & ~(size_t)255; };
    size_t sortedB = al((size_t)NBUK * CAP * 2);
    size_t gcurB   = al((size_t)NBUK * 4 + 16);
    size_t embT_b  = al((size_t)NF * DIM * 2);
    size_t wpk_b   = al((size_t)LH * 512 * 16);
    size_t histB   = al(((size_t)M * 625 + 1) / 2 + 16);

    float* outp = (float*)d_out;

    if (ws_size >= sortedB + gcurB + embT_b + wpk_b) {
        // -------- sorted mode: zero -> (sort + fused prep) -> gnn --------
        unsigned short* sorted = (unsigned short*)d_ws;
        unsigned* gcur = (unsigned*)((char*)d_ws + sortedB);
        short*    embT = (short*)((char*)d_ws + sortedB + gcurB);
        short*    wpk  = (short*)((char*)d_ws + sortedB + gcurB + embT_b);

        int nzero = (int)(gcurB / 16);
        prep_k<<<(nzero + 255) / 256, 256, 0, stream>>>(
            W_fp, emb, gcur, wpk, embT, /*LH=*/0, NF, nzero, /*doEmb=*/0);
        scatter_k<<<NBLK, 256, NBUK * 4, stream>>>(
            esrc, edst, gcur, sorted, W_fp, emb, wpk, embT, E, NBUK, LH, NF);
        gnn_k<true, true><<<grid, WAVES * 64, 0, stream>>>(
            emb, embT, b_fp, W_out, b_out, W_prop, b_prop, fps,
            nullptr, sorted, gcur, wpk, outp, LH, LO, M);
    } else {
        // -------- fallback: global nibble hist --------
        bool fast = ws_size >= histB + embT_b + wpk_b;
        unsigned* Bg = (unsigned*)d_ws;
        short* embT = fast ? (short*)((char*)d_ws + histB) : nullptr;
        short* wpk  = fast ? (short*)((char*)d_ws + histB + embT_b)
                           : (short*)((char*)d_ws + histB);
        int nzero = (int)(histB / 16);
        int workP = nzero;
        if (fast && NF * 8 > workP) workP = NF * 8;
        if (LH * 512 > workP) workP = LH * 512;
        prep_k<<<(workP + 255) / 256, 256, 0, stream>>>(
            W_fp, emb, Bg, wpk, embT, LH, NF, nzero, fast ? 1 : 0);
        ehist_k<<<(E + 255) / 256, 256, 0, stream>>>(esrc, edst, Bg, E);
        if (fast)
            gnn_k<false, true><<<grid, WAVES * 64, 0, stream>>>(
                emb, embT, b_fp, W_out, b_out, W_prop, b_prop, fps,
                Bg, nullptr, nullptr, wpk, outp, LH, LO, M);
        else
            gnn_k<false, false><<<grid, WAVES * 64, 0, stream>>>(
                emb, embT, b_fp, W_out, b_out, W_prop, b_prop, fps,
                Bg, nullptr, nullptr, wpk, outp, LH, LO, M);
    }
}

// Round 17
// 94.137 us; speedup vs baseline: 1.1875x; 1.1875x over previous
//
#include <hip/hip_runtime.h>
#include <hip/hip_bf16.h>
#include <stdint.h>

#define S_ATOMS 25
#define DIM 64
#define AP 40      // hT row stride (shorts): 80B rows (16B-aligned for b128)
#define VP 72      // v' row stride (shorts): 144B rows
#define WAVES 4    // waves per block (256 threads)
#define PM 5       // molecules per wave (sequential, 1 live at a time)
#define BMOLS 20   // molecules per gnn block = WAVES*PM = bucket size
#define XB2 2560   // shorts per wave buffer: max(64*AP, 32*VP) = 2560 (5120B)
#define EPB 8192   // edges per scatter block (245 blocks ~ 1/CU)
#define CAP 2560   // sorted capacity per bucket (E[edges]=2000, +12 sigma)

typedef __attribute__((ext_vector_type(8))) short short8;   // 8 bf16
typedef __attribute__((ext_vector_type(4))) short short4s;  // 4 bf16 (b64)
typedef __attribute__((ext_vector_type(4))) float f32x4;
typedef __attribute__((ext_vector_type(4))) unsigned uint4v;

static __device__ __forceinline__ short bf(float x) {
    return (short)__builtin_bit_cast(unsigned short, __float2bfloat16(x));
}
// v_cvt_pk_bf16_f32: dst.lo = bf16(lo), dst.hi = bf16(hi) — 1 instr, RNE
static __device__ __forceinline__ unsigned cvtpk(float lo, float hi) {
    unsigned r;
    asm("v_cvt_pk_bf16_f32 %0, %1, %2" : "=v"(r) : "v"(lo), "v"(hi));
    return r;
}

// ---------------- prep_k: zero cursors + W-pack + emb->bf16 -----------------
__global__ __launch_bounds__(256) void prep_k(
    const float* __restrict__ W_fp, const float* __restrict__ emb,
    unsigned* __restrict__ zbuf, short* __restrict__ wpk, short* __restrict__ embT,
    int LH, int NF, int nzero, int doEmb)
{
    int gid = blockIdx.x * 256 + threadIdx.x;
    if (gid < nzero) {                // zero bucket cursors (or fallback hist)
        uint4v z; z[0]=0; z[1]=0; z[2]=0; z[3]=0;
        ((uint4v*)zbuf)[gid] = z;
    }
    if (gid < LH * 512) {             // prepack W_fp MFMA B-fragments
        int t = gid;
        int layer = t >> 9, q = t & 511;
        int nt = q >> 7, ks = (q >> 6) & 1, lane = q & 63;
        int cc = lane & 15, gg = lane >> 4;
        const float* p = W_fp + (size_t)layer * 4096 + (nt * 16 + cc) * 64 + ks * 32 + 8 * gg;
        short8 s;
        #pragma unroll
        for (int j = 0; j < 8; ++j) s[j] = bf(p[j]);
        *(short8*)(wpk + (size_t)t * 8) = s;
    }
    if (doEmb && gid < NF * 8) {      // emb f32 -> bf16 row-major
        int row = gid >> 3, seg = gid & 7;
        const float* p = emb + (size_t)row * DIM + seg * 8;
        short8 s;
        #pragma unroll
        for (int j = 0; j < 8; ++j) s[j] = bf(p[j]);
        *(short8*)(embT + (size_t)row * DIM + seg * 8) = s;
    }
}

// ---------------- scatter_k: self-ticketing counting sort -------------------
// bucket b = mol / 20 (= src/500). key16 = (mol%20)*640 + dl*25 + sl (<12800)
// Bucket fill ORDER is nondeterministic; gnn's histogram SUM is not.
__global__ __launch_bounds__(256) void scatter_k(
    const int* __restrict__ esrc, const int* __restrict__ edst,
    unsigned* __restrict__ gcur, unsigned short* __restrict__ sorted,
    int E, int NBUK)
{
    extern __shared__ unsigned cnt[];               // NBUK words
    for (int j = threadIdx.x; j < NBUK; j += 256) cnt[j] = 0;
    __syncthreads();
    int base = blockIdx.x * EPB;
    int end = base + EPB; if (end > E) end = E;
    int e = base + threadIdx.x * 4;
    for (; e + 4 <= end; e += 1024) {               // int4 reads, 4 edges/thread
        int4 s4 = *(const int4*)(esrc + e);
        atomicAdd(&cnt[s4.x / (S_ATOMS * BMOLS)], 1u);
        atomicAdd(&cnt[s4.y / (S_ATOMS * BMOLS)], 1u);
        atomicAdd(&cnt[s4.z / (S_ATOMS * BMOLS)], 1u);
        atomicAdd(&cnt[s4.w / (S_ATOMS * BMOLS)], 1u);
    }
    for (; e < end; ++e)
        atomicAdd(&cnt[esrc[e] / (S_ATOMS * BMOLS)], 1u);
    __syncthreads();
    // ticket: claim [base, base+cnt) per bucket; LDS holds write cursor
    for (int j = threadIdx.x; j < NBUK; j += 256) {
        unsigned cj = cnt[j];
        unsigned b0 = cj ? atomicAdd(&gcur[j], cj) : 0u;
        if (b0 > CAP) b0 = CAP;
        cnt[j] = (unsigned)j * CAP + b0;
    }
    __syncthreads();
    for (int e2 = base + threadIdx.x; e2 < end; e2 += 256) {
        int s = esrc[e2], d = edst[e2];
        int m  = s / S_ATOMS;
        int sl = s - m * S_ATOMS;
        int dl = d - m * S_ATOMS;
        int b  = s / (S_ATOMS * BMOLS);
        int ml = m - b * BMOLS;
        unsigned pos = atomicAdd(&cnt[b], 1u);
        if (pos < (unsigned)(b + 1) * CAP)
            sorted[pos] = (unsigned short)(ml * 640 + dl * 25 + sl);
    }
}

// ---------------- fused per-molecule GNN ------------------------------------
// SORTED: block=bucket(20 mols), B-hists built in LDS from sorted keys
// GEMM1: h[atom][dout] = v*W^T (A=v, B=Wpack)       -> 16 MFMA
// GEMM2: u^T[dim][atom] = h^T * B^T = mfma(b2,amat) -> 8 MFMA,  B = I + A
template<bool SORTED, bool FAST>
__global__ __launch_bounds__(256, 4) void gnn_k(
    const float* __restrict__ emb,     // [NF,64] f32 (FAST=false)
    const short* __restrict__ embT,    // [NF,64] bf16 (FAST=true)
    const float* __restrict__ b_fp, const float* __restrict__ W_out,
    const float* __restrict__ b_out, const float* __restrict__ W_prop,
    const float* __restrict__ b_prop, const int* __restrict__ fps,
    const unsigned* __restrict__ Bg,   // global nibble hist (SORTED=false)
    const unsigned short* __restrict__ sorted,  // [NBUK*CAP] (SORTED=true)
    const unsigned* __restrict__ gcur, // [NBUK] final counts (SORTED=true)
    const short* __restrict__ wpk, float* __restrict__ out,
    int LH, int LO, int M)
{
    __shared__ __align__(16) short xb_all[WAVES][XB2];
    __shared__ __align__(16) float mv_all[WAVES][PM][DIM];
    __shared__ unsigned bh[BMOLS * 80];   // 20 mols x 640 nibbles (80 words)
    const int w = threadIdx.x >> 6, l = threadIdx.x & 63;
    const int c = l & 15, g = l >> 4;
    short* xb = xb_all[w];
    const short8* wp8 = (const short8*)wpk;
    const int wave_id = blockIdx.x * WAVES + w;

    if (SORTED) {
        for (int j = threadIdx.x; j < BMOLS * 80; j += 256) bh[j] = 0;
        __syncthreads();
        unsigned cb = gcur[blockIdx.x]; if (cb > CAP) cb = CAP;
        const unsigned short* sp = sorted + (size_t)blockIdx.x * CAP;
        for (int i = threadIdx.x; i < (int)cb; i += 256) {
            unsigned k = sp[i];
            atomicAdd(&bh[k >> 3], 1u << ((k & 7) * 4));
        }
        __syncthreads();
    }

    for (int mi = 0; mi < PM; ++mi) {
        const int mol = wave_id * PM + mi;
        if (mol >= M) break;           // wave-uniform

        // ---- amat: B^T-operand frags, B = I + A ----
        const int ml = w * PM + mi;    // mol within block (SORTED)
        short8 amat[2];
        #pragma unroll
        for (int at = 0; at < 2; ++at) {
            int row = at * 16 + c;
            float f[8];
            if (row < S_ATOMS) {
                unsigned lo, hi; int sh;
                if (SORTED) {
                    int n0 = ml * 640 + row * 25 + 8 * g;
                    lo = bh[n0 >> 3]; hi = bh[(n0 >> 3) + 1];
                    sh = (n0 & 7) * 4;
                } else {
                    int n0 = mol * 625 + row * 25 + 8 * g;
                    lo = Bg[n0 >> 3]; hi = Bg[(n0 >> 3) + 1];
                    sh = (n0 & 7) * 4;
                }
                unsigned long long v64 = ((unsigned long long)hi << 32) | lo;
                v64 >>= sh;
                #pragma unroll
                for (int j = 0; j < 8; ++j) {
                    unsigned n = (unsigned)(v64 >> (4 * j)) & 0xFu;
                    f[j] = (8 * g + j) < S_ATOMS ? (float)n : 0.f;
                    if (8 * g + j == row) f[j] += 1.0f;   // +I
                }
            } else {
                #pragma unroll
                for (int j = 0; j < 8; ++j) f[j] = 0.f;
            }
            short8 s;
            #pragma unroll
            for (int j = 0; j < 8; ++j) s[j] = bf(f[j]);
            amat[at] = s;
        }

        // ---- layer-0 A-frags from the embedding table ----
        short8 a1[2][2];
        #pragma unroll
        for (int mt = 0; mt < 2; ++mt) {
            int atom = mt * 16 + c;
            int aa = atom < S_ATOMS ? atom : S_ATOMS - 1;  // pads killed by B cols=0
            int fi = fps[mol * S_ATOMS + aa];
            #pragma unroll
            for (int ks = 0; ks < 2; ++ks) {
                if (FAST) {
                    a1[mt][ks] = *(const short8*)(embT + (size_t)fi * DIM + ks * 32 + 8 * g);
                } else {
                    const float4* qp = (const float4*)(emb + (size_t)fi * DIM + ks * 32 + 8 * g);
                    float4 f0 = qp[0], f1 = qp[1];
                    short8 s;
                    s[0]=bf(f0.x); s[1]=bf(f0.y); s[2]=bf(f0.z); s[3]=bf(f0.w);
                    s[4]=bf(f1.x); s[5]=bf(f1.y); s[6]=bf(f1.z); s[7]=bf(f1.w);
                    a1[mt][ks] = s;
                }
            }
        }

        for (int layer = 0; layer < LH; ++layer) {
            // ---- GEMM1: acc = v*W^T + b ----
            float bv[4];
            #pragma unroll
            for (int nt = 0; nt < 4; ++nt) bv[nt] = b_fp[layer * DIM + nt * 16 + c];
            f32x4 acc[2][4];
            #pragma unroll
            for (int mt = 0; mt < 2; ++mt)
                #pragma unroll
                for (int nt = 0; nt < 4; ++nt) {
                    f32x4 a; a[0]=bv[nt]; a[1]=bv[nt]; a[2]=bv[nt]; a[3]=bv[nt];
                    acc[mt][nt] = a;
                }
            #pragma unroll
            for (int ks = 0; ks < 2; ++ks) {
                short8 bwk[4];
                #pragma unroll
                for (int nt = 0; nt < 4; ++nt)
                    bwk[nt] = wp8[layer * 512 + nt * 128 + ks * 64 + l];
                #pragma unroll
                for (int mt = 0; mt < 2; ++mt)
                    #pragma unroll
                    for (int nt = 0; nt < 4; ++nt)
                        acc[mt][nt] = __builtin_amdgcn_mfma_f32_16x16x32_bf16(
                            a1[mt][ks], bwk[nt], acc[mt][nt], 0, 0, 0);
            }

            // ---- epilogue1: relu, cvt_pk pack, write hT[dout][atom] ----
            #pragma unroll
            for (int mt = 0; mt < 2; ++mt)
                #pragma unroll
                for (int nt = 0; nt < 4; ++nt) {
                    unsigned w0 = cvtpk(fmaxf(acc[mt][nt][0], 0.f),
                                        fmaxf(acc[mt][nt][1], 0.f));
                    unsigned w1 = cvtpk(fmaxf(acc[mt][nt][2], 0.f),
                                        fmaxf(acc[mt][nt][3], 0.f));
                    *(uint2*)&xb[(nt * 16 + c) * AP + mt * 16 + 4 * g] = make_uint2(w0, w1);
                }
            __builtin_amdgcn_wave_barrier();

            // ---- GEMM2: u^T = h^T * B^T ----
            short8 b2[4];
            #pragma unroll
            for (int dt = 0; dt < 4; ++dt)
                b2[dt] = *(const short8*)&xb[(dt * 16 + c) * AP + 8 * g];
            f32x4 ua[4][2];
            #pragma unroll
            for (int dt = 0; dt < 4; ++dt)
                #pragma unroll
                for (int at = 0; at < 2; ++at) {
                    f32x4 z; z[0]=0.f; z[1]=0.f; z[2]=0.f; z[3]=0.f;
                    ua[dt][at] = __builtin_amdgcn_mfma_f32_16x16x32_bf16(
                        b2[dt], amat[at], z, 0, 0, 0);
                }

            // ---- per-atom norms (atom = at*16+c; reduce over g-groups) ----
            float ss0 = 0.f, ss1 = 0.f;
            #pragma unroll
            for (int dt = 0; dt < 4; ++dt)
                #pragma unroll
                for (int r = 0; r < 4; ++r) {
                    ss0 += ua[dt][0][r] * ua[dt][0][r];
                    ss1 += ua[dt][1][r] * ua[dt][1][r];
                }
            ss0 += __shfl_xor(ss0, 16); ss0 += __shfl_xor(ss0, 32);
            ss1 += __shfl_xor(ss1, 16); ss1 += __shfl_xor(ss1, 32);
            float rn0 = __builtin_amdgcn_rsqf(fmaxf(ss0, 1e-24f));
            float rn1 = __builtin_amdgcn_rsqf(fmaxf(ss1, 1e-24f));

            bool lastl = (layer == LH - 1);
            __builtin_amdgcn_wave_barrier();
            if (!lastl) {
                // ---- v' -> xb[atom][dim] via cvt_pk (b2 already in regs) ----
                #pragma unroll
                for (int at = 0; at < 2; ++at) {
                    float r0 = at ? rn1 : rn0;
                    #pragma unroll
                    for (int dt = 0; dt < 4; ++dt) {
                        unsigned w0 = cvtpk(ua[dt][at][0] * r0, ua[dt][at][1] * r0);
                        unsigned w1 = cvtpk(ua[dt][at][2] * r0, ua[dt][at][3] * r0);
                        *(uint2*)&xb[(at * 16 + c) * VP + dt * 16 + 4 * g] = make_uint2(w0, w1);
                    }
                }
                __builtin_amdgcn_wave_barrier();
                #pragma unroll
                for (int mt = 0; mt < 2; ++mt)
                    #pragma unroll
                    for (int ks = 0; ks < 2; ++ks)
                        a1[mt][ks] = *(const short8*)&xb[(mt * 16 + c) * VP + ks * 32 + 8 * g];
            } else {
                // ---- molecule sum via 15-shfl split-butterfly over c-lanes ----
                float mx[16];
                #pragma unroll
                for (int dt = 0; dt < 4; ++dt)
                    #pragma unroll
                    for (int r = 0; r < 4; ++r)
                        mx[dt * 4 + r] = ua[dt][0][r] * rn0 + ua[dt][1][r] * rn1;
                #pragma unroll
                for (int k = 0; k < 8; ++k) {
                    float send = (c & 8) ? mx[k] : mx[k + 8];
                    float keep = (c & 8) ? mx[k + 8] : mx[k];
                    mx[k] = keep + __shfl_xor(send, 8);
                }
                #pragma unroll
                for (int k = 0; k < 4; ++k) {
                    float send = (c & 4) ? mx[k] : mx[k + 4];
                    float keep = (c & 4) ? mx[k + 4] : mx[k];
                    mx[k] = keep + __shfl_xor(send, 4);
                }
                #pragma unroll
                for (int k = 0; k < 2; ++k) {
                    float send = (c & 2) ? mx[k] : mx[k + 2];
                    float keep = (c & 2) ? mx[k + 2] : mx[k];
                    mx[k] = keep + __shfl_xor(send, 2);
                }
                {
                    float send = (c & 1) ? mx[0] : mx[1];
                    float keep = (c & 1) ? mx[1] : mx[0];
                    mx[0] = keep + __shfl_xor(send, 1);
                }
                int dim = (c >> 2) * 16 + 4 * g + (c & 3);
                mv_all[w][mi][dim] = mx[0];
                __builtin_amdgcn_wave_barrier();
            }
        }
    }

    // ---- output MLP, batched over the wave's PM molecules (lane = dout) ----
    float cur[PM];
    for (int layer = 0; layer < LO; ++layer) {
        const float4* wr = (const float4*)(W_out + ((size_t)layer * DIM + l) * DIM);
        float bb = b_out[layer * DIM + l];
        float av[PM];
        #pragma unroll
        for (int q = 0; q < PM; ++q) av[q] = bb;
        #pragma unroll
        for (int k = 0; k < 16; ++k) {
            float4 ww = wr[k];
            #pragma unroll
            for (int q = 0; q < PM; ++q) {
                float4 vv = ((const float4*)mv_all[w][q])[k];
                av[q] += vv.x * ww.x + vv.y * ww.y + vv.z * ww.z + vv.w * ww.w;
            }
        }
        __builtin_amdgcn_wave_barrier();
        #pragma unroll
        for (int q = 0; q < PM; ++q) { cur[q] = fmaxf(av[q], 0.f); mv_all[w][q][l] = cur[q]; }
        __builtin_amdgcn_wave_barrier();
    }
    float wpv = W_prop[l], bp = b_prop[0];
    #pragma unroll
    for (int q = 0; q < PM; ++q) {
        float p = cur[q] * wpv;
        p += __shfl_xor(p, 1);  p += __shfl_xor(p, 2);
        p += __shfl_xor(p, 4);  p += __shfl_xor(p, 8);
        p += __shfl_xor(p, 16); p += __shfl_xor(p, 32);
        int mol = wave_id * PM + q;
        if (l == 0 && mol < M) out[mol] = p + bp;
    }
}

// ---------------- fallback ehist (global memory-side atomics) ---------------
__global__ __launch_bounds__(256) void ehist_k(
    const int* __restrict__ esrc, const int* __restrict__ edst,
    unsigned* __restrict__ Bg, int E)
{
    int e = blockIdx.x * 256 + threadIdx.x;
    if (e >= E) return;
    int s = esrc[e], d = edst[e];
    int m  = s / S_ATOMS;
    int sl = s - m * S_ATOMS;
    int dl = d - m * S_ATOMS;
    int n = m * 625 + dl * 25 + sl;
    atomicAdd(&Bg[n >> 3], 1u << ((n & 7) * 4));
}

// ---------------- launch ----------------------------------------------------
extern "C" void kernel_launch(void* const* d_in, const int* in_sizes, int n_in,
                              void* d_out, int out_size, void* d_ws, size_t ws_size,
                              hipStream_t stream)
{
    const float* emb    = (const float*)d_in[0];
    const float* W_fp   = (const float*)d_in[1];
    const float* b_fp   = (const float*)d_in[2];
    const float* W_out  = (const float*)d_in[3];
    const float* b_out  = (const float*)d_in[4];
    const float* W_prop = (const float*)d_in[5];
    const float* b_prop = (const float*)d_in[6];
    const int*   fps    = (const int*)d_in[7];
    const int*   esrc   = (const int*)d_in[8];
    const int*   edst   = (const int*)d_in[9];

    const int T  = in_sizes[7];
    const int E  = in_sizes[8];
    const int NF = in_sizes[0] / DIM;
    const int LH = in_sizes[1] / (DIM * DIM);
    const int LO = in_sizes[3] / (DIM * DIM);
    const int M  = T / S_ATOMS;

    const int NBUK = (M + BMOLS - 1) / BMOLS;
    const int NBLK = (E + EPB - 1) / EPB;
    const int grid = (M + WAVES * PM - 1) / (WAVES * PM);  // == NBUK

    auto al = [](size_t x) { return (x + 255) & ~(size_t)255; };
    size_t sortedB = al((size_t)NBUK * CAP * 2);
    size_t gcurB   = al((size_t)NBUK * 4 + 16);
    size_t embT_b  = al((size_t)NF * DIM * 2);
    size_t wpk_b   = al((size_t)LH * 512 * 16);
    size_t histB   = al(((size_t)M * 625 + 1) / 2 + 16);

    float* outp = (float*)d_out;

    if (ws_size >= sortedB + gcurB + embT_b + wpk_b) {
        // -------- sorted mode: prep -> sort -> gnn (round-15 pipeline) ------
        unsigned short* sorted = (unsigned short*)d_ws;
        unsigned* gcur = (unsigned*)((char*)d_ws + sortedB);
        short*    embT = (short*)((char*)d_ws + sortedB + gcurB);
        short*    wpk  = (short*)((char*)d_ws + sortedB + gcurB + embT_b);

        int nzero = (int)(gcurB / 16);
        int workP = NF * 8;
        if (LH * 512 > workP) workP = LH * 512;
        if (nzero > workP) workP = nzero;
        prep_k<<<(workP + 255) / 256, 256, 0, stream>>>(
            W_fp, emb, gcur, wpk, embT, LH, NF, nzero, 1);
        scatter_k<<<NBLK, 256, NBUK * 4, stream>>>(esrc, edst, gcur, sorted, E, NBUK);
        gnn_k<true, true><<<grid, WAVES * 64, 0, stream>>>(
            emb, embT, b_fp, W_out, b_out, W_prop, b_prop, fps,
            nullptr, sorted, gcur, wpk, outp, LH, LO, M);
    } else {
        // -------- fallback: global nibble hist --------
        bool fast = ws_size >= histB + embT_b + wpk_b;
        unsigned* Bg = (unsigned*)d_ws;
        short* embT = fast ? (short*)((char*)d_ws + histB) : nullptr;
        short* wpk  = fast ? (short*)((char*)d_ws + histB + embT_b)
                           : (short*)((char*)d_ws + histB);
        int nzero = (int)(histB / 16);
        int workP = nzero;
        if (fast && NF * 8 > workP) workP = NF * 8;
        if (LH * 512 > workP) workP = LH * 512;
        prep_k<<<(workP + 255) / 256, 256, 0, stream>>>(
            W_fp, emb, Bg, wpk, embT, LH, NF, nzero, fast ? 1 : 0);
        ehist_k<<<(E + 255) / 256, 256, 0, stream>>>(esrc, edst, Bg, E);
        if (fast)
            gnn_k<false, true><<<grid, WAVES * 64, 0, stream>>>(
                emb, embT, b_fp, W_out, b_out, W_prop, b_prop, fps,
                Bg, nullptr, nullptr, wpk, outp, LH, LO, M);
        else
            gnn_k<false, false><<<grid, WAVES * 64, 0, stream>>>(
                emb, embT, b_fp, W_out, b_out, W_prop, b_prop, fps,
                Bg, nullptr, nullptr, wpk, outp, LH, LO, M);
    }
}